// Round 1
// baseline (190.593 us; speedup 1.0000x reference)
//
#include <hip/hip_runtime.h>
#include <hip/hip_bf16.h>

// NNConv / MPNN layer, fully fused:
//   h  = relu(ef @ W1 + b1)            [E,128]   (bf16 MFMA, K=16, LDS-only)
//   We = h @ W2 + b2                   [E,32,32] (bf16 MFMA, K=128, AGPR-only, never stored)
//   msg= einsum('ei,eio->eo', nf[src], We)       (fp32 VALU on AGPR tiles)
//   out= segment_sum(msg, dst) + bias            (fp32 global atomics, out pre-init to bias)
//
// E=200000 = 3125 tiles x 64 edges. Block = 512 thr = 8 waves, 1 tile/block.
// Wave w owns i-tiles {4w..4w+3} (N-cols (4w+j)*32..+32) x 2 M-subtiles -> 8 f32x16 acc = 128 AGPR.
// All LDS tiles XOR-swizzled (k-group ^ addr-bits) for even bank spread on ds_read_b128.

#define E_TOTAL   200000
#define N_NODES   50000
#define TILES     3125          // E_TOTAL / 64
#define OUT_ELEMS 1600000       // N_NODES * 32
#define OUT_BLKS  6250          // OUT_ELEMS / 256
#define W2K_BLKS  512           // 131072 / 256

typedef short short8  __attribute__((ext_vector_type(8)));
typedef float f32x16  __attribute__((ext_vector_type(16)));

__device__ __forceinline__ short f2bf(float f) {
    // round-to-nearest-even fp32 -> bf16 (inputs finite)
    union { float f; unsigned u; } cv; cv.f = f;
    unsigned r = cv.u + 0x7fffu + ((cv.u >> 16) & 1u);
    return (short)(r >> 16);
}

// ---------------- setup: init out = bias, convert W2 -> bf16 chunk-major in ws ----------------
// ws layout W2k[ks 8][col 1024][k 16] bf16, ks*16+k = global K row of W2.
__global__ __launch_bounds__(256) void setup_kernel(const float* __restrict__ W2,
                                                    const float* __restrict__ bias,
                                                    float* __restrict__ out,
                                                    short* __restrict__ W2k) {
    int bid = blockIdx.x, tid = threadIdx.x;
    if (bid < OUT_BLKS) {
        int i = bid * 256 + tid;
        out[i] = bias[i & 31];
    } else {
        int g = (bid - OUT_BLKS) * 256 + tid;     // 0..131071, coalesced read of W2
        int col = g & 1023, kg = g >> 10;
        int ks = kg >> 4, kl = kg & 15;
        W2k[ks * 16384 + col * 16 + kl] = f2bf(W2[g]);
    }
}

// ---------------- main fused kernel: one 64-edge tile per block ----------------
__global__ __launch_bounds__(512, 2) void mpnn_kernel(const float* __restrict__ nf,
                                                      const float* __restrict__ ef,
                                                      const int*   __restrict__ esrc,
                                                      const int*   __restrict__ edst,
                                                      const float* __restrict__ W1,
                                                      const float* __restrict__ b1,
                                                      const float* __restrict__ b2,
                                                      const short* __restrict__ W2k,
                                                      float* __restrict__ out) {
    // ---- shared memory plan (64512 B total, <= 64 KB) ----
    __shared__ __align__(16) unsigned char smem[64512];
    short* W2s  = (short*)(smem);            // 32768 B: [1024 c][16 k] bf16, swizzled   (K-loop)
    short* Hs   = (short*)(smem + 32768);    // 16384 B: [64 e][128 k] bf16, swizzled
    float* Xs   = (float*)(smem + 49152);    //  8192 B: [64 e][32 i] f32
    short* Efs  = (short*)(smem + 57344);    //  2048 B: [64 e][16 k] bf16, swizzled
    short* W1Ts = (short*)(smem + 59392);    //  4096 B: [128 c][16 k] bf16, swizzled
    float* b1s  = (float*)(smem + 63488);    //   512 B
    int*   srcs = (int*)  (smem + 64000);    //   256 B
    int*   dsts = (int*)  (smem + 64256);    //   256 B
    float* pbuf = (float*)(smem);            // alias W2s: [4][64][32] f32 partials (stage 2)
    float* b2s  = (float*)(smem + 57344);    // alias Efs+W1Ts: 4096 B (stage 2)

    const int tid  = threadIdx.x;
    const int w    = tid >> 6;          // wave 0..7
    const int l31  = tid & 31;
    const int lh   = (tid >> 5) & 1;    // k-half within wave
    const int ebase = blockIdx.x * 64;

    // ---------------- phase 0: stage inputs ----------------
    if (tid < 64)  { srcs[tid] = esrc[ebase + tid]; dsts[tid] = edst[ebase + tid]; }
    if (tid < 128) { b1s[tid] = b1[tid]; }
    {   // ef tile -> Efs bf16 (swizzled): thread t handles edge t>>3, 2 elems
        int e = tid >> 3, ii = (tid & 7) * 2;
        float2 v = *(const float2*)(ef + (size_t)(ebase + e) * 16 + ii);
        int idx = e * 16 + (((ii >> 3) ^ ((e >> 2) & 1)) << 3) + (ii & 7);
        unsigned pk = (unsigned short)f2bf(v.x) | ((unsigned)(unsigned short)f2bf(v.y) << 16);
        *(unsigned*)(Efs + idx) = pk;   // idx even
    }
    {   // W1 [16][128] f32 -> W1Ts[c][i] bf16 (swizzled)
        int g = tid * 4; int i = g >> 7; int c0 = g & 127;
        float4 v = *(const float4*)(W1 + g);
        float vv[4] = {v.x, v.y, v.z, v.w};
        #pragma unroll
        for (int u = 0; u < 4; ++u) {
            int c = c0 + u;
            W1Ts[c * 16 + (((i >> 3) ^ ((c >> 2) & 1)) << 3) + (i & 7)] = f2bf(vv[u]);
        }
    }
    __syncthreads();
    {   // gather x = nf[src] -> Xs f32 (needs srcs)
        int e = tid >> 3, i4 = (tid & 7) * 4;
        float4 v = *(const float4*)(nf + (size_t)srcs[e] * 32 + i4);
        *(float4*)(Xs + e * 32 + i4) = v;
    }

    // ---------------- phase 1: edge MLP, one MFMA per wave ----------------
    {
        int mh = w & 1, nt = w >> 1;
        int e = l31 + (mh << 5);
        short8 a = *(const short8*)(Efs + e * 16 + ((lh ^ ((e >> 2) & 1)) << 3));
        int c = (nt << 5) + l31;
        short8 b = *(const short8*)(W1Ts + c * 16 + ((lh ^ ((c >> 2) & 1)) << 3));
        f32x16 hacc;
        #pragma unroll
        for (int i = 0; i < 16; ++i) hacc[i] = 0.f;
        hacc = __builtin_amdgcn_mfma_f32_32x32x16_bf16(a, b, hacc, 0, 0, 0);
        #pragma unroll
        for (int r = 0; r < 16; ++r) {
            int row = (r & 3) + ((r >> 2) << 3) + (lh << 2);
            int ee = row + (mh << 5);
            float v = hacc[r] + b1s[c];
            v = fmaxf(v, 0.f);
            Hs[ee * 128 + (((c >> 3) ^ (ee & 15)) << 3) + (c & 7)] = f2bf(v);
        }
    }

    // ---------------- phase 2: K-loop, We tile in AGPRs ----------------
    f32x16 acc[4][2];
    #pragma unroll
    for (int j = 0; j < 4; ++j)
        #pragma unroll
        for (int mh = 0; mh < 2; ++mh)
            #pragma unroll
            for (int i = 0; i < 16; ++i) acc[j][mh][i] = 0.f;

    // chunk staging: thread t handles cols t and t+512, 32 B each, halves swapped by (c>>2)&1
    const int c0 = tid, c1 = tid + 512;
    const int s0 = (c0 >> 2) & 1, s1 = (c1 >> 2) & 1;
    const int st0a = c0 * 16 + (s0 << 3), st0b = c0 * 16 + ((1 - s0) << 3);
    const int st1a = c1 * 16 + (s1 << 3), st1b = c1 * 16 + ((1 - s1) << 3);
    int4 ld0a = *(const int4*)(W2k + c0 * 16);
    int4 ld0b = *(const int4*)(W2k + c0 * 16 + 8);
    int4 ld1a = *(const int4*)(W2k + c1 * 16);
    int4 ld1b = *(const int4*)(W2k + c1 * 16 + 8);

    for (int ks = 0; ks < 8; ++ks) {
        __syncthreads();                       // prior MFMA reads of W2s drained
        *(int4*)(W2s + st0a) = ld0a; *(int4*)(W2s + st0b) = ld0b;
        *(int4*)(W2s + st1a) = ld1a; *(int4*)(W2s + st1b) = ld1b;
        __syncthreads();                       // chunk ks ready
        if (ks < 7) {                          // prefetch next chunk; drains at next barrier
            const short* p = W2k + (ks + 1) * 16384;
            ld0a = *(const int4*)(p + c0 * 16); ld0b = *(const int4*)(p + c0 * 16 + 8);
            ld1a = *(const int4*)(p + c1 * 16); ld1b = *(const int4*)(p + c1 * 16 + 8);
        }
        short8 afr[2];
        #pragma unroll
        for (int mh = 0; mh < 2; ++mh) {
            int e = l31 + (mh << 5);
            int G = ks * 2 + lh;               // = k>>3
            afr[mh] = *(const short8*)(Hs + e * 128 + ((G ^ (e & 15)) << 3));
        }
        #pragma unroll
        for (int j = 0; j < 4; ++j) {
            int c = ((4 * w + j) << 5) + l31;
            short8 bfr = *(const short8*)(W2s + c * 16 + ((lh ^ ((c >> 2) & 1)) << 3));
            acc[j][0] = __builtin_amdgcn_mfma_f32_32x32x16_bf16(afr[0], bfr, acc[j][0], 0, 0, 0);
            acc[j][1] = __builtin_amdgcn_mfma_f32_32x32x16_bf16(afr[1], bfr, acc[j][1], 0, 0, 0);
        }
    }

    // ---------------- phase 3: contract with x, reduce across waves, atomic out ----------------
    __syncthreads();                           // last MFMA frag reads drained; W2s/Efs reusable
    b2s[tid] = b2[tid]; b2s[tid + 512] = b2[tid + 512];
    __syncthreads();

    const int o = l31;
    float b2v[4];
    #pragma unroll
    for (int j = 0; j < 4; ++j) b2v[j] = b2s[((4 * w + j) << 5) + o];

    float sva[2][16];
    #pragma unroll
    for (int mh = 0; mh < 2; ++mh)
        #pragma unroll
        for (int r = 0; r < 16; ++r) {
            int e = (r & 3) + ((r >> 2) << 3) + (lh << 2) + (mh << 5);
            float4 xv = *(const float4*)(Xs + e * 32 + 4 * w);   // x[e][4w..4w+3]
            sva[mh][r] = xv.x * (acc[0][mh][r] + b2v[0])
                       + xv.y * (acc[1][mh][r] + b2v[1])
                       + xv.z * (acc[2][mh][r] + b2v[2])
                       + xv.w * (acc[3][mh][r] + b2v[3]);
        }

    if (w < 4) {
        #pragma unroll
        for (int mh = 0; mh < 2; ++mh)
            #pragma unroll
            for (int r = 0; r < 16; ++r) {
                int e = (r & 3) + ((r >> 2) << 3) + (lh << 2) + (mh << 5);
                pbuf[(w << 11) + (e << 5) + o] = sva[mh][r];
            }
    }
    __syncthreads();
    if (w >= 4) {
        #pragma unroll
        for (int mh = 0; mh < 2; ++mh)
            #pragma unroll
            for (int r = 0; r < 16; ++r) {
                int e = (r & 3) + ((r >> 2) << 3) + (lh << 2) + (mh << 5);
                pbuf[((w - 4) << 11) + (e << 5) + o] += sva[mh][r];
            }
    }
    __syncthreads();
    #pragma unroll
    for (int p = 0; p < 4; ++p) {
        int idx = tid + (p << 9);
        float v = pbuf[idx] + pbuf[idx + 2048] + pbuf[idx + 4096] + pbuf[idx + 6144];
        int e = idx >> 5, oo = idx & 31;
        atomicAdd(out + (size_t)dsts[e] * 32 + oo, v);
    }
}

extern "C" void kernel_launch(void* const* d_in, const int* in_sizes, int n_in,
                              void* d_out, int out_size, void* d_ws, size_t ws_size,
                              hipStream_t stream) {
    const float* nf   = (const float*)d_in[0];
    const float* ef   = (const float*)d_in[1];
    const int*   src  = (const int*)  d_in[2];
    const int*   dst  = (const int*)  d_in[3];
    const float* W1   = (const float*)d_in[4];
    const float* b1   = (const float*)d_in[5];
    const float* W2   = (const float*)d_in[6];
    const float* b2   = (const float*)d_in[7];
    const float* bias = (const float*)d_in[8];
    float* out = (float*)d_out;
    short* W2k = (short*)d_ws;                 // 262144 B bf16 W2, chunk-major

    setup_kernel<<<OUT_BLKS + W2K_BLKS, 256, 0, stream>>>(W2, bias, out, W2k);
    mpnn_kernel<<<TILES, 512, 0, stream>>>(nf, ef, src, dst, W1, b1, b2, W2k, out);
}